// Round 5
// baseline (267.512 us; speedup 1.0000x reference)
//
#include <hip/hip_runtime.h>

// ParallelAttention router: q,k,v = x@Wq|Wk|Wv (16384x2048 @ 2048x64),
// out[t][i] = sum_j softmax_j(q_i*k_j) * v_j, fp32 in/out.
//
// Strategy: split-bf16 (hi/lo) MFMA GEMM fused with per-token softmax epilogue.
//   pack_w_kernel: lay out Wq|Wk|Wv as MFMA B-fragments (bf16 hi+lo) in d_ws.
//   router_kernel: 512 blocks x 512 thr (8 waves); block = 32 tokens.
//     SPLIT-K IN BLOCK: waves 0-3 accumulate K-chunks 0..31, waves 4-7 chunks
//     32..63. Each wave = 32 rows x 48 cols (6 16x16x32 tiles, 3 MFMAs each
//     for hi*hi+lo*hi+hi*lo) — the per-wave inner loop is VERBATIM the
//     verified 258us round-0 body (1-deep prefetch; 2-deep was a measured
//     null: compiler re-coalesces buffers, m99-m141 behavior). Partials go to
//     qkv[2] in LDS; epilogue sums them (fp32 add, order-only numerics change).
//   Rationale: K-loop is latency-bound (2 waves/SIMD at grid=512; MfmaUtil 13%,
//   VALUBusy 25%, HBM 8%). ILP via source prefetch is compiler-defeated; this
//   doubles TLP (4 waves/SIMD) with zero change to per-wave math or traffic.
//   (Rounds 3+4 were infra failures — this source is a verbatim resubmit;
//   round 1 proved 512-thr/launch_bounds(512,4) kernels run on this harness,
//   so the container failures are not source-triggered.)

typedef __bf16 bf16x8 __attribute__((ext_vector_type(8)));
typedef float f32x4  __attribute__((ext_vector_type(4)));

#define NTOK   16384
#define HDIM   2048
#define NCHUNK 64              // total K chunks of 32
#define KCH    32              // chunks per K-half (per wave group)
#define CH_STRIDE (12 * 2 * 512)  // bf16 elems per chunk in bfrag

// bfrag layout: [chunk 0..63][tile 0..11][hi=0/lo=1][lane 0..63][j 0..7]
// element = W_cat[k = chunk*32 + (lane>>4)*8 + j][n = tile*16 + (lane&15)]
// where W_cat cols: 0-63 = Wq, 64-127 = Wk, 128-191 = Wv.
__global__ void pack_w_kernel(const float* __restrict__ Wq,
                              const float* __restrict__ Wk,
                              const float* __restrict__ Wv,
                              __bf16* __restrict__ bfrag)
{
  int u = blockIdx.x * blockDim.x + threadIdx.x;   // (chunk, tile, lane)
  if (u >= NCHUNK * 12 * 64) return;
  int l  = u & 63;
  int tn = (u >> 6) % 12;
  int c  = u / (12 * 64);
  int n  = tn * 16 + (l & 15);
  int kb = c * 32 + ((l >> 4) << 3);
  const float* W = (n < 64) ? Wq : (n < 128) ? Wk : Wv;
  int nn = n & 63;
  bf16x8 hi, lo;
#pragma unroll
  for (int j = 0; j < 8; ++j) {
    float f = W[(size_t)(kb + j) * 64 + nn];
    __bf16 h = (__bf16)f;              // RNE
    hi[j] = h;
    lo[j] = (__bf16)(f - (float)h);    // residual
  }
  size_t base = (size_t)(c * 12 + tn) * 1024 + (size_t)l * 8;
  *(bf16x8*)(bfrag + base)       = hi;
  *(bf16x8*)(bfrag + base + 512) = lo;
}

__global__ __launch_bounds__(512, 4) void router_kernel(
    const float* __restrict__ x,
    const __bf16* __restrict__ bfrag,
    float* __restrict__ out)
{
  const int tok0 = blockIdx.x * 32;
  const int w    = threadIdx.x >> 6;   // wave 0..7
  const int lane = threadIdx.x & 63;
  const int kh   = w >> 2;             // K-half: chunks [32*kh, 32*kh+32)
  const int wc   = w & 3;              // col group: cols [48*wc, 48*wc+48)
  const int mr   = lane & 15;
  const int quad = lane >> 4;

  __shared__ float qkv[2][32 * 196];   // [K-half][32 tokens x 192 (+4 pad)]

  // A: row-tile i covers tokens tok0+16i .. +15; lane reads 8 consecutive k.
  // K-half offset: kh * (KCH*32) = kh*1024 elements.
  const float*  a0 = x + (size_t)(tok0 + mr) * HDIM + quad * 8 + kh * 1024;
  const float*  a1 = a0 + 16 * HDIM;
  const __bf16* bp = bfrag + (size_t)(kh * KCH) * CH_STRIDE
                           + (size_t)(3 * wc) * 1024 + (size_t)lane * 8;

  f32x4 acc[2][3];
#pragma unroll
  for (int i = 0; i < 2; ++i)
#pragma unroll
    for (int t = 0; t < 3; ++t)
      acc[i][t] = (f32x4){0.f, 0.f, 0.f, 0.f};

  // register prefetch (1 chunk deep) — verbatim round-0 body below.
  float4 pA[4];
  bf16x8 pBh[3], pBl[3];
  pA[0] = *(const float4*)(a0);
  pA[1] = *(const float4*)(a0 + 4);
  pA[2] = *(const float4*)(a1);
  pA[3] = *(const float4*)(a1 + 4);
#pragma unroll
  for (int t = 0; t < 3; ++t) {
    pBh[t] = *(const bf16x8*)(bp + (size_t)t * 1024);
    pBl[t] = *(const bf16x8*)(bp + (size_t)t * 1024 + 512);
  }

  for (int c = 0; c < KCH; ++c) {
    float4 A[4]; bf16x8 Bh[3], Bl[3];
#pragma unroll
    for (int i = 0; i < 4; ++i) A[i] = pA[i];
#pragma unroll
    for (int t = 0; t < 3; ++t) { Bh[t] = pBh[t]; Bl[t] = pBl[t]; }

    if (c + 1 < KCH) {
      const float*  na0 = a0 + (c + 1) * 32;
      const float*  na1 = a1 + (c + 1) * 32;
      const __bf16* nbp = bp + (size_t)(c + 1) * CH_STRIDE;
      pA[0] = *(const float4*)(na0);
      pA[1] = *(const float4*)(na0 + 4);
      pA[2] = *(const float4*)(na1);
      pA[3] = *(const float4*)(na1 + 4);
#pragma unroll
      for (int t = 0; t < 3; ++t) {
        pBh[t] = *(const bf16x8*)(nbp + (size_t)t * 1024);
        pBl[t] = *(const bf16x8*)(nbp + (size_t)t * 1024 + 512);
      }
    }

    // fp32 -> bf16 hi/lo split
    bf16x8 ah[2], al[2];
#pragma unroll
    for (int i = 0; i < 2; ++i) {
      float av[8] = {A[2*i].x, A[2*i].y, A[2*i].z, A[2*i].w,
                     A[2*i+1].x, A[2*i+1].y, A[2*i+1].z, A[2*i+1].w};
#pragma unroll
      for (int j = 0; j < 8; ++j) {
        __bf16 h = (__bf16)av[j];
        ah[i][j] = h;
        al[i][j] = (__bf16)(av[j] - (float)h);
      }
    }

#pragma unroll
    for (int i = 0; i < 2; ++i)
#pragma unroll
      for (int t = 0; t < 3; ++t) {
        acc[i][t] = __builtin_amdgcn_mfma_f32_16x16x32_bf16(ah[i], Bh[t], acc[i][t], 0, 0, 0);
        acc[i][t] = __builtin_amdgcn_mfma_f32_16x16x32_bf16(al[i], Bh[t], acc[i][t], 0, 0, 0);
        acc[i][t] = __builtin_amdgcn_mfma_f32_16x16x32_bf16(ah[i], Bl[t], acc[i][t], 0, 0, 0);
      }
  }

  // C/D layout (m89-verified): col = lane&15, row = (lane>>4)*4 + reg
#pragma unroll
  for (int i = 0; i < 2; ++i)
#pragma unroll
    for (int t = 0; t < 3; ++t) {
      int col = wc * 48 + t * 16 + mr;
      int row = i * 16 + quad * 4;
#pragma unroll
      for (int r = 0; r < 4; ++r)
        qkv[kh][(row + r) * 196 + col] = acc[i][t][r];
    }
  __syncthreads();

  // softmax epilogue: 16 threads per token, 4 outputs each; q/k/v are the
  // sum of the two K-half partials (fp32 add — order-only numerics change).
  // No max-subtraction needed: |q_i*k_j| <~ 26, exp2(26*1.44) well inside fp32.
  const int tt = threadIdx.x >> 4;     // token 0..31
  const int g  = threadIdx.x & 15;     // output group
  const float* q0 = qkv[0] + tt * 196;
  const float* q1 = qkv[1] + tt * 196;
  float qs[4], lsum[4], osum[4];
#pragma unroll
  for (int ii = 0; ii < 4; ++ii) {
    qs[ii]   = (q0[g * 4 + ii] + q1[g * 4 + ii]) * 1.44269504f;   // log2(e)
    lsum[ii] = 0.f;
    osum[ii] = 0.f;
  }
  for (int j = 0; j < 64; ++j) {
    float kj = q0[64 + j]  + q1[64 + j];
    float vj = q0[128 + j] + q1[128 + j];
#pragma unroll
    for (int ii = 0; ii < 4; ++ii) {
      float e = __builtin_amdgcn_exp2f(qs[ii] * kj);   // v_exp_f32
      lsum[ii] += e;
      osum[ii] = fmaf(e, vj, osum[ii]);
    }
  }
  float4 r0;
  r0.x = osum[0] / lsum[0]; r0.y = osum[1] / lsum[1];
  r0.z = osum[2] / lsum[2]; r0.w = osum[3] / lsum[3];
  float* op = out + (size_t)(tok0 + tt) * 64 + g * 4;
  *(float4*)op = r0;
}

extern "C" void kernel_launch(void* const* d_in, const int* in_sizes, int n_in,
                              void* d_out, int out_size, void* d_ws, size_t ws_size,
                              hipStream_t stream)
{
  const float* x  = (const float*)d_in[0];
  const float* Wq = (const float*)d_in[1];
  const float* Wk = (const float*)d_in[2];
  const float* Wv = (const float*)d_in[3];
  __bf16* bfrag   = (__bf16*)d_ws;          // needs 1.5 MiB of scratch
  float*  out     = (float*)d_out;

  pack_w_kernel<<<(NCHUNK * 12 * 64 + 255) / 256, 256, 0, stream>>>(Wq, Wk, Wv, bfrag);
  router_kernel<<<NTOK / 32, 512, 0, stream>>>(x, bfrag, out);
}

// Round 6
// 241.125 us; speedup vs baseline: 1.1094x; 1.1094x over previous
//
#include <hip/hip_runtime.h>

// ParallelAttention router: q,k,v = x@Wq|Wk|Wv (16384x2048 @ 2048x64),
// out[t][i] = sum_j softmax_j(q_i*k_j) * v_j, fp32 in/out.
//
// Strategy: split-bf16 (hi/lo) MFMA GEMM fused with per-token softmax epilogue.
//   pack_w_kernel: lay out Wq|Wk|Wv as MFMA B-fragments (bf16 hi+lo) in d_ws.
//   router_kernel: 512 blocks x 512 thr (8 waves); block = 32 tokens; split-K
//     (waves 0-3 chunks 0..31, waves 4-7 chunks 32..63), wave = 32r x 48c.
//   ROUND-6 CHANGE (one lever): A path global->reg (compiler re-serializes it;
//   VGPR=56 proves no chunk prefetch survived) becomes global_load_lds into
//   double-buffered LDS (m97 structure: stage c+1 BEFORE compute c, drain at
//   the barrier AFTER — flight overlaps compute within each wave; the one
//   pipelining idiom the compiler provably preserves). A-tile LDS reads are
//   XOR-swizzled (SWZ below, applied at BOTH stage-source and read — rule
//   #21) to kill the 16-way bank conflict of a [32][32] f32 tile.
//   B stays direct-to-register from L2 (resident 1.5 MB; ~250cy covered by
//   4 waves/SIMD).

typedef __bf16 bf16x8 __attribute__((ext_vector_type(8)));
typedef float f32x4  __attribute__((ext_vector_type(4)));

#define NTOK   16384
#define HDIM   2048
#define NCHUNK 64              // total K chunks of 32
#define KCH    32              // chunks per K-half (per wave group)
#define CH_STRIDE (12 * 2 * 512)  // bf16 elems per chunk in bfrag

// LDS A-tile swizzle: slot kq' of row r holds global k-group kq'^(r&7).
// Self-inverse; spreads the 16 same-quad lanes across 8 distinct 16B slots.
#define SWZ(row, kq) ((kq) ^ ((row) & 7))

#define GLOAD_LDS16(g, l)                                                      \
  __builtin_amdgcn_global_load_lds(                                            \
      (const __attribute__((address_space(1))) void*)(g),                      \
      (__attribute__((address_space(3))) void*)(l), 16, 0, 0)

// bfrag layout: [chunk 0..63][tile 0..11][hi=0/lo=1][lane 0..63][j 0..7]
// element = W_cat[k = chunk*32 + (lane>>4)*8 + j][n = tile*16 + (lane&15)]
// where W_cat cols: 0-63 = Wq, 64-127 = Wk, 128-191 = Wv.
__global__ void pack_w_kernel(const float* __restrict__ Wq,
                              const float* __restrict__ Wk,
                              const float* __restrict__ Wv,
                              __bf16* __restrict__ bfrag)
{
  int u = blockIdx.x * blockDim.x + threadIdx.x;   // (chunk, tile, lane)
  if (u >= NCHUNK * 12 * 64) return;
  int l  = u & 63;
  int tn = (u >> 6) % 12;
  int c  = u / (12 * 64);
  int n  = tn * 16 + (l & 15);
  int kb = c * 32 + ((l >> 4) << 3);
  const float* W = (n < 64) ? Wq : (n < 128) ? Wk : Wv;
  int nn = n & 63;
  bf16x8 hi, lo;
#pragma unroll
  for (int j = 0; j < 8; ++j) {
    float f = W[(size_t)(kb + j) * 64 + nn];
    __bf16 h = (__bf16)f;              // RNE
    hi[j] = h;
    lo[j] = (__bf16)(f - (float)h);    // residual
  }
  size_t base = (size_t)(c * 12 + tn) * 1024 + (size_t)l * 8;
  *(bf16x8*)(bfrag + base)       = hi;
  *(bf16x8*)(bfrag + base + 512) = lo;
}

__global__ __launch_bounds__(512, 4) void router_kernel(
    const float* __restrict__ x,
    const __bf16* __restrict__ bfrag,
    float* __restrict__ out)
{
  const int tok0 = blockIdx.x * 32;
  const int w    = threadIdx.x >> 6;   // wave 0..7
  const int lane = threadIdx.x & 63;
  const int kh   = w >> 2;             // K-half: chunks [KCH*kh, KCH*kh+KCH)
  const int wc   = w & 3;              // col group: cols [48*wc, 48*wc+48)
  const int mr   = lane & 15;
  const int quad = lane >> 4;

  __shared__ float qkv[2][32 * 196];   // [K-half][32 tokens x 192 (+4 pad)]
  __shared__ float bufA[2][2][1024];   // [K-half][dbuf][32 rows x 32 k, SWZ'd]

  // --- A staging (global_load_lds): thread u' = tid&255 covers its half's
  // 4KB chunk tile. Row = u'>>3, LDS slot = u'&7; the slot CONTAINS global
  // k-group SWZ(row, slot). Wave-uniform LDS base + lane*16 (HW semantics).
  const int su   = threadIdx.x & 255;
  const int srow = su >> 3;            // 0..31
  const int skq  = su & 7;             // LDS 16B-slot within row
  const float* aSrc = x + (size_t)(tok0 + srow) * HDIM + kh * 1024
                        + SWZ(srow, skq) * 4;
  float* aDst0 = &bufA[kh][0][(w & 3) * 256];   // wave-uniform
  float* aDst1 = &bufA[kh][1][(w & 3) * 256];

  // B: direct register loads from L2-resident bfrag (MFMA-fragment packed).
  const __bf16* bp = bfrag + (size_t)(kh * KCH) * CH_STRIDE
                           + (size_t)(3 * wc) * 1024 + (size_t)lane * 8;

  f32x4 acc[2][3];
#pragma unroll
  for (int i = 0; i < 2; ++i)
#pragma unroll
    for (int t = 0; t < 3; ++t)
      acc[i][t] = (f32x4){0.f, 0.f, 0.f, 0.f};

  // prologue: stage chunk 0 into buf0; barrier drains it (vmcnt(0)+s_barrier).
  GLOAD_LDS16(aSrc, aDst0);
  __syncthreads();

  for (int c = 0; c < KCH; ++c) {
    // stage A chunk c+1 into buf[(c+1)&1] — in flight during compute(c),
    // drained by the barrier at iteration end.
    if (c + 1 < KCH) {
      const float* s = aSrc + (c + 1) * 32;
      if (c & 1) GLOAD_LDS16(s, aDst0);
      else       GLOAD_LDS16(s, aDst1);
    }

    // B fragments for chunk c (plain loads; L2-hit, covered by 4 waves/SIMD).
    const __bf16* cbp = bp + (size_t)c * CH_STRIDE;
    bf16x8 Bh[3], Bl[3];
#pragma unroll
    for (int t = 0; t < 3; ++t) {
      Bh[t] = *(const bf16x8*)(cbp + (size_t)t * 1024);
      Bl[t] = *(const bf16x8*)(cbp + (size_t)t * 1024 + 512);
    }

    // A fragments from LDS buf[c&1]: row-tile i rows i*16+mr, k = quad*8..+7.
    const float* ab = bufA[kh][c & 1];
    const int r0 = mr, r1 = 16 + mr;   // r0&7 == r1&7
    float4 A[4];
    A[0] = *(const float4*)&ab[r0 * 32 + SWZ(r0, 2 * quad)     * 4];
    A[1] = *(const float4*)&ab[r0 * 32 + SWZ(r0, 2 * quad + 1) * 4];
    A[2] = *(const float4*)&ab[r1 * 32 + SWZ(r1, 2 * quad)     * 4];
    A[3] = *(const float4*)&ab[r1 * 32 + SWZ(r1, 2 * quad + 1) * 4];

    // fp32 -> bf16 hi/lo split (verbatim round-5 math)
    bf16x8 ah[2], al[2];
#pragma unroll
    for (int i = 0; i < 2; ++i) {
      float av[8] = {A[2*i].x, A[2*i].y, A[2*i].z, A[2*i].w,
                     A[2*i+1].x, A[2*i+1].y, A[2*i+1].z, A[2*i+1].w};
#pragma unroll
      for (int j = 0; j < 8; ++j) {
        __bf16 h = (__bf16)av[j];
        ah[i][j] = h;
        al[i][j] = (__bf16)(av[j] - (float)h);
      }
    }

#pragma unroll
    for (int i = 0; i < 2; ++i)
#pragma unroll
      for (int t = 0; t < 3; ++t) {
        acc[i][t] = __builtin_amdgcn_mfma_f32_16x16x32_bf16(ah[i], Bh[t], acc[i][t], 0, 0, 0);
        acc[i][t] = __builtin_amdgcn_mfma_f32_16x16x32_bf16(al[i], Bh[t], acc[i][t], 0, 0, 0);
        acc[i][t] = __builtin_amdgcn_mfma_f32_16x16x32_bf16(ah[i], Bl[t], acc[i][t], 0, 0, 0);
      }

    // drain stage(c+1) + sync readers/writers of the LDS buffers.
    __syncthreads();
  }

  // C/D layout (m89-verified): col = lane&15, row = (lane>>4)*4 + reg
#pragma unroll
  for (int i = 0; i < 2; ++i)
#pragma unroll
    for (int t = 0; t < 3; ++t) {
      int col = wc * 48 + t * 16 + mr;
      int row = i * 16 + quad * 4;
#pragma unroll
      for (int r = 0; r < 4; ++r)
        qkv[kh][(row + r) * 196 + col] = acc[i][t][r];
    }
  __syncthreads();

  // softmax epilogue: 16 threads per token, 4 outputs each; q/k/v are the
  // sum of the two K-half partials (fp32 add — order-only numerics change).
  // No max-subtraction needed: |q_i*k_j| <~ 26, exp2(26*1.44) well inside fp32.
  const int tt = threadIdx.x >> 4;     // token 0..31
  const int g  = threadIdx.x & 15;     // output group
  const float* q0 = qkv[0] + tt * 196;
  const float* q1 = qkv[1] + tt * 196;
  float qs[4], lsum[4], osum[4];
#pragma unroll
  for (int ii = 0; ii < 4; ++ii) {
    qs[ii]   = (q0[g * 4 + ii] + q1[g * 4 + ii]) * 1.44269504f;   // log2(e)
    lsum[ii] = 0.f;
    osum[ii] = 0.f;
  }
  for (int j = 0; j < 64; ++j) {
    float kj = q0[64 + j]  + q1[64 + j];
    float vj = q0[128 + j] + q1[128 + j];
#pragma unroll
    for (int ii = 0; ii < 4; ++ii) {
      float e = __builtin_amdgcn_exp2f(qs[ii] * kj);   // v_exp_f32
      lsum[ii] += e;
      osum[ii] = fmaf(e, vj, osum[ii]);
    }
  }
  float4 r0v;
  r0v.x = osum[0] / lsum[0]; r0v.y = osum[1] / lsum[1];
  r0v.z = osum[2] / lsum[2]; r0v.w = osum[3] / lsum[3];
  float* op = out + (size_t)(tok0 + tt) * 64 + g * 4;
  *(float4*)op = r0v;
}

extern "C" void kernel_launch(void* const* d_in, const int* in_sizes, int n_in,
                              void* d_out, int out_size, void* d_ws, size_t ws_size,
                              hipStream_t stream)
{
  const float* x  = (const float*)d_in[0];
  const float* Wq = (const float*)d_in[1];
  const float* Wk = (const float*)d_in[2];
  const float* Wv = (const float*)d_in[3];
  __bf16* bfrag   = (__bf16*)d_ws;          // needs 1.5 MiB of scratch
  float*  out     = (float*)d_out;

  pack_w_kernel<<<(NCHUNK * 12 * 64 + 255) / 256, 256, 0, stream>>>(Wq, Wk, Wv, bfrag);
  router_kernel<<<NTOK / 32, 512, 0, stream>>>(x, bfrag, out);
}

// Round 7
// 240.818 us; speedup vs baseline: 1.1108x; 1.0013x over previous
//
#include <hip/hip_runtime.h>

// ParallelAttention router: q,k,v = x@Wq|Wk|Wv (16384x2048 @ 2048x64),
// out[t][i] = sum_j softmax_j(q_i*k_j) * v_j, fp32 in/out.
//
// Strategy: split-bf16 (hi/lo) MFMA GEMM fused with per-token softmax epilogue.
//   pack_w_kernel: lay out Wq|Wk|Wv as MFMA B-fragments (bf16 hi+lo) in d_ws.
//   router_kernel: 512 blocks x 512 thr (8 waves); block = 32 tokens; split-K
//     (waves 0-3 chunks 0..31, waves 4-7 chunks 32..63), wave = 32r x 48c.
//   A path: global_load_lds into double-buffered LDS (round 6: +21%), SWZ'd.
//   ROUND-7 CHANGE (one lever): B fragments were loaded and consumed in the
//   same chunk (~300cy L2 latency exposed; the per-chunk __syncthreads vmcnt(0)
//   drain prevents cross-chunk flight of plain loads). Now B is prefetched ONE
//   CHUNK AHEAD into named register double-sets (B0/B1, explicit 2x unroll,
//   static indexing per rule #20). Unlike round 2's failed prefetch (barrier-
//   free loop -> compiler re-fused issue+use), the barrier between issue and
//   use pins the schedule; the end-of-chunk drain is then free because the
//   loads flew during the whole chunk's compute.

typedef __bf16 bf16x8 __attribute__((ext_vector_type(8)));
typedef float f32x4  __attribute__((ext_vector_type(4)));

#define NTOK   16384
#define HDIM   2048
#define NCHUNK 64              // total K chunks of 32
#define KCH    32              // chunks per K-half (per wave group)
#define CH_STRIDE (12 * 2 * 512)  // bf16 elems per chunk in bfrag

// LDS A-tile swizzle: slot kq' of row r holds global k-group kq'^(r&7).
// Self-inverse; near-floor bank spread for the [32][32] f32 tile's b128 reads.
#define SWZ(row, kq) ((kq) ^ ((row) & 7))

#define GLOAD_LDS16(g, l)                                                      \
  __builtin_amdgcn_global_load_lds(                                            \
      (const __attribute__((address_space(1))) void*)(g),                      \
      (__attribute__((address_space(3))) void*)(l), 16, 0, 0)

// bfrag layout: [chunk 0..63][tile 0..11][hi=0/lo=1][lane 0..63][j 0..7]
// element = W_cat[k = chunk*32 + (lane>>4)*8 + j][n = tile*16 + (lane&15)]
// where W_cat cols: 0-63 = Wq, 64-127 = Wk, 128-191 = Wv.
__global__ void pack_w_kernel(const float* __restrict__ Wq,
                              const float* __restrict__ Wk,
                              const float* __restrict__ Wv,
                              __bf16* __restrict__ bfrag)
{
  int u = blockIdx.x * blockDim.x + threadIdx.x;   // (chunk, tile, lane)
  if (u >= NCHUNK * 12 * 64) return;
  int l  = u & 63;
  int tn = (u >> 6) % 12;
  int c  = u / (12 * 64);
  int n  = tn * 16 + (l & 15);
  int kb = c * 32 + ((l >> 4) << 3);
  const float* W = (n < 64) ? Wq : (n < 128) ? Wk : Wv;
  int nn = n & 63;
  bf16x8 hi, lo;
#pragma unroll
  for (int j = 0; j < 8; ++j) {
    float f = W[(size_t)(kb + j) * 64 + nn];
    __bf16 h = (__bf16)f;              // RNE
    hi[j] = h;
    lo[j] = (__bf16)(f - (float)h);    // residual
  }
  size_t base = (size_t)(c * 12 + tn) * 1024 + (size_t)l * 8;
  *(bf16x8*)(bfrag + base)       = hi;
  *(bf16x8*)(bfrag + base + 512) = lo;
}

// Load B fragments of chunk (cc) into register set S (S##h, S##l).
#define LOADB(S, cc)                                                           \
  {                                                                            \
    const __bf16* nbp = bp + (size_t)(cc) * CH_STRIDE;                         \
    _Pragma("unroll")                                                          \
    for (int t = 0; t < 3; ++t) {                                              \
      S##h[t] = *(const bf16x8*)(nbp + (size_t)t * 1024);                      \
      S##l[t] = *(const bf16x8*)(nbp + (size_t)t * 1024 + 512);                \
    }                                                                          \
  }

// Compute one chunk from LDS buffer `ab` with B register set S. Verbatim
// round-6 math (A swizzled reads, hi/lo split, 18 MFMA).
#define COMPUTE(ab, S)                                                         \
  {                                                                            \
    const int r0 = mr, r1 = 16 + mr;                                           \
    float4 A[4];                                                               \
    A[0] = *(const float4*)&(ab)[r0 * 32 + SWZ(r0, 2 * quad)     * 4];         \
    A[1] = *(const float4*)&(ab)[r0 * 32 + SWZ(r0, 2 * quad + 1) * 4];         \
    A[2] = *(const float4*)&(ab)[r1 * 32 + SWZ(r1, 2 * quad)     * 4];         \
    A[3] = *(const float4*)&(ab)[r1 * 32 + SWZ(r1, 2 * quad + 1) * 4];         \
    bf16x8 ah[2], al[2];                                                       \
    _Pragma("unroll")                                                          \
    for (int i = 0; i < 2; ++i) {                                              \
      float av[8] = {A[2*i].x, A[2*i].y, A[2*i].z, A[2*i].w,                   \
                     A[2*i+1].x, A[2*i+1].y, A[2*i+1].z, A[2*i+1].w};          \
      _Pragma("unroll")                                                        \
      for (int j = 0; j < 8; ++j) {                                            \
        __bf16 h = (__bf16)av[j];                                              \
        ah[i][j] = h;                                                          \
        al[i][j] = (__bf16)(av[j] - (float)h);                                 \
      }                                                                        \
    }                                                                          \
    _Pragma("unroll")                                                          \
    for (int i = 0; i < 2; ++i)                                                \
      _Pragma("unroll")                                                        \
      for (int t = 0; t < 3; ++t) {                                            \
        acc[i][t] = __builtin_amdgcn_mfma_f32_16x16x32_bf16(ah[i], S##h[t], acc[i][t], 0, 0, 0); \
        acc[i][t] = __builtin_amdgcn_mfma_f32_16x16x32_bf16(al[i], S##h[t], acc[i][t], 0, 0, 0); \
        acc[i][t] = __builtin_amdgcn_mfma_f32_16x16x32_bf16(ah[i], S##l[t], acc[i][t], 0, 0, 0); \
      }                                                                        \
  }

__global__ __launch_bounds__(512, 4) void router_kernel(
    const float* __restrict__ x,
    const __bf16* __restrict__ bfrag,
    float* __restrict__ out)
{
  const int tok0 = blockIdx.x * 32;
  const int w    = threadIdx.x >> 6;   // wave 0..7
  const int lane = threadIdx.x & 63;
  const int kh   = w >> 2;             // K-half: chunks [KCH*kh, KCH*kh+KCH)
  const int wc   = w & 3;              // col group: cols [48*wc, 48*wc+48)
  const int mr   = lane & 15;
  const int quad = lane >> 4;

  __shared__ float qkv[2][32 * 196];   // [K-half][32 tokens x 192 (+4 pad)]
  __shared__ float bufA[2][2][1024];   // [K-half][dbuf][32 rows x 32 k, SWZ'd]

  // --- A staging (global_load_lds): thread u' = tid&255 covers its half's
  // 4KB chunk tile. Row = u'>>3, LDS slot = u'&7; the slot CONTAINS global
  // k-group SWZ(row, slot). Wave-uniform LDS base + lane*16 (HW semantics).
  const int su   = threadIdx.x & 255;
  const int srow = su >> 3;            // 0..31
  const int skq  = su & 7;             // LDS 16B-slot within row
  const float* aSrc = x + (size_t)(tok0 + srow) * HDIM + kh * 1024
                        + SWZ(srow, skq) * 4;
  float* aDst0 = &bufA[kh][0][(w & 3) * 256];   // wave-uniform
  float* aDst1 = &bufA[kh][1][(w & 3) * 256];

  // B: direct register loads from L2-resident bfrag (MFMA-fragment packed).
  const __bf16* bp = bfrag + (size_t)(kh * KCH) * CH_STRIDE
                           + (size_t)(3 * wc) * 1024 + (size_t)lane * 8;

  f32x4 acc[2][3];
#pragma unroll
  for (int i = 0; i < 2; ++i)
#pragma unroll
    for (int t = 0; t < 3; ++t)
      acc[i][t] = (f32x4){0.f, 0.f, 0.f, 0.f};

  // B register double-sets (named; static indexing only — rule #20).
  bf16x8 B0h[3], B0l[3], B1h[3], B1l[3];

  // prologue: stage A(0) into buf0; preload B(0) into set0; barrier drains.
  GLOAD_LDS16(aSrc, aDst0);
  LOADB(B0, 0)
  __syncthreads();

  for (int c = 0; c < KCH; c += 2) {
    // even half: compute chunk c from buf0 with B0; stage A(c+1)->buf1 and
    // prefetch B(c+1)->B1 (both fly across this half's compute + barrier).
    if (c + 1 < KCH) {
      GLOAD_LDS16(aSrc + (c + 1) * 32, aDst1);
      LOADB(B1, c + 1)
    }
    COMPUTE(bufA[kh][0], B0)
    __syncthreads();

    // odd half: compute chunk c+1 from buf1 with B1; stage A(c+2)->buf0 and
    // prefetch B(c+2)->B0.
    if (c + 2 < KCH) {
      GLOAD_LDS16(aSrc + (c + 2) * 32, aDst0);
      LOADB(B0, c + 2)
    }
    COMPUTE(bufA[kh][1], B1)
    __syncthreads();
  }

  // C/D layout (m89-verified): col = lane&15, row = (lane>>4)*4 + reg
#pragma unroll
  for (int i = 0; i < 2; ++i)
#pragma unroll
    for (int t = 0; t < 3; ++t) {
      int col = wc * 48 + t * 16 + mr;
      int row = i * 16 + quad * 4;
#pragma unroll
      for (int r = 0; r < 4; ++r)
        qkv[kh][(row + r) * 196 + col] = acc[i][t][r];
    }
  __syncthreads();

  // softmax epilogue: 16 threads per token, 4 outputs each; q/k/v are the
  // sum of the two K-half partials (fp32 add — order-only numerics change).
  // No max-subtraction needed: |q_i*k_j| <~ 26, exp2(26*1.44) well inside fp32.
  const int tt = threadIdx.x >> 4;     // token 0..31
  const int g  = threadIdx.x & 15;     // output group
  const float* q0 = qkv[0] + tt * 196;
  const float* q1 = qkv[1] + tt * 196;
  float qs[4], lsum[4], osum[4];
#pragma unroll
  for (int ii = 0; ii < 4; ++ii) {
    qs[ii]   = (q0[g * 4 + ii] + q1[g * 4 + ii]) * 1.44269504f;   // log2(e)
    lsum[ii] = 0.f;
    osum[ii] = 0.f;
  }
  for (int j = 0; j < 64; ++j) {
    float kj = q0[64 + j]  + q1[64 + j];
    float vj = q0[128 + j] + q1[128 + j];
#pragma unroll
    for (int ii = 0; ii < 4; ++ii) {
      float e = __builtin_amdgcn_exp2f(qs[ii] * kj);   // v_exp_f32
      lsum[ii] += e;
      osum[ii] = fmaf(e, vj, osum[ii]);
    }
  }
  float4 r0v;
  r0v.x = osum[0] / lsum[0]; r0v.y = osum[1] / lsum[1];
  r0v.z = osum[2] / lsum[2]; r0v.w = osum[3] / lsum[3];
  float* op = out + (size_t)(tok0 + tt) * 64 + g * 4;
  *(float4*)op = r0v;
}

extern "C" void kernel_launch(void* const* d_in, const int* in_sizes, int n_in,
                              void* d_out, int out_size, void* d_ws, size_t ws_size,
                              hipStream_t stream)
{
  const float* x  = (const float*)d_in[0];
  const float* Wq = (const float*)d_in[1];
  const float* Wk = (const float*)d_in[2];
  const float* Wv = (const float*)d_in[3];
  __bf16* bfrag   = (__bf16*)d_ws;          // needs 1.5 MiB of scratch
  float*  out     = (float*)d_out;

  pack_w_kernel<<<(NCHUNK * 12 * 64 + 255) / 256, 256, 0, stream>>>(Wq, Wk, Wv, bfrag);
  router_kernel<<<NTOK / 32, 512, 0, stream>>>(x, bfrag, out);
}